// Round 12
// baseline (589.603 us; speedup 1.0000x reference)
//
#include <hip/hip_runtime.h>
#include <stdint.h>

typedef __attribute__((ext_vector_type(8))) short short8;
typedef __attribute__((ext_vector_type(4))) float f32x4;

#define TT 512
#define LSTR 136   // sZ/sY row stride in ushorts: 272B -> spread banks
#define XS 516     // sX row stride in floats

static __device__ __forceinline__ uint32_t f2bf_u(float f){
  union { float f; uint32_t u; } v; v.f = f;
  return (v.u + 0x7fffu + ((v.u >> 16) & 1u)) >> 16;
}
static __device__ __forceinline__ short8 w8f32(const float* p){
  float4 a = *(const float4*)p;
  float4 b = *(const float4*)(p + 4);
  short8 r;
  r[0] = (short)f2bf_u(a.x); r[1] = (short)f2bf_u(a.y);
  r[2] = (short)f2bf_u(a.z); r[3] = (short)f2bf_u(a.w);
  r[4] = (short)f2bf_u(b.x); r[5] = (short)f2bf_u(b.y);
  r[6] = (short)f2bf_u(b.z); r[7] = (short)f2bf_u(b.w);
  return r;
}
// sigmoid via exp2+rcp: inf-safe (exp2->inf => rcp->0).
static __device__ __forceinline__ float sigx(float x){
  float e = __builtin_amdgcn_exp2f(-1.442695040888963f * x);
  return __builtin_amdgcn_rcpf(1.f + e);
}
// tanh(x) = 2*sigmoid(2x)-1: no clamp needed.
static __device__ __forceinline__ float tanhx(float x){
  float e = __builtin_amdgcn_exp2f(-2.885390081777927f * x);
  return fmaf(__builtin_amdgcn_rcpf(1.f + e), 2.f, -1.f);
}
// LDS-only barrier: waits ds ops, leaves global loads/stores in flight.
static __device__ __forceinline__ void lds_barrier(){
  asm volatile("s_waitcnt lgkmcnt(0)" ::: "memory");
  __builtin_amdgcn_s_barrier();
}
#define MF(A,B,C) __builtin_amdgcn_mfma_f32_16x16x32_bf16((A),(B),(C),0,0,0)
// lane^8 exchange (convergent -> must be issued unconditionally)
#define SWZ(x) __int_as_float(__builtin_amdgcn_ds_swizzle(__float_as_int(x), 0x201F))

// ==================== Layer 0 ====================
// (unchanged from round 11) 256 thr / 4 waves / 4 batches; grid (256,2) ->
// 2 blocks/CU. 4 MFMA chains 0-init; own-unit VALU FF (12 fmaf); cndmask
// chain select; 4-row sZ with broadcast reads.
__global__ __launch_bounds__(256, 2) void lstm_l0(
    const float* __restrict__ x,   // [B][3][T]
    const float* __restrict__ Wih_f, const float* __restrict__ Whh_f,
    const float* __restrict__ bih_f, const float* __restrict__ bhh_f,
    const float* __restrict__ Wih_b, const float* __restrict__ Whh_b,
    const float* __restrict__ bih_b, const float* __restrict__ bhh_b,
    unsigned short* __restrict__ y0)  // [B][T][128] bf16
{
  const int tid = threadIdx.x;
  const int wv = tid >> 6, lane = tid & 63;
  const int quad = lane >> 4, m16 = lane & 15;
  const int dir = blockIdx.y;
  const int bbase = blockIdx.x * 4;
  const float* Wih = dir ? Wih_b : Wih_f;
  const float* Whh = dir ? Whh_b : Whh_f;
  const float* bih = dir ? bih_b : bih_f;
  const float* bhh = dir ? bhh_b : bhh_f;

  __shared__ __align__(16) unsigned short sZ[2][4][LSTR];
  __shared__ __align__(16) float sX[12 * XS];

  const int copy = m16 >> 2;
  const int batch = m16 & 3;
  const int unit = 16 * wv + 4 * copy + quad;
  const bool selA = (copy & 1) != 0;
  const bool selB = (copy & 2) != 0;

  short8 aH[4][2];
  const int gm = (m16 & 3) * 64 + (m16 >> 2);
  #pragma unroll
  for (int k = 0; k < 4; k++){
    const int g = gm + 4 * (4 * wv + k);
    aH[k][0] = w8f32(Whh + g * 64 + quad * 8);
    aH[k][1] = w8f32(Whh + g * 64 + 32 + quad * 8);
  }
  float Wf[4][3];
  f32x4 biasF;
  #pragma unroll
  for (int r = 0; r < 4; r++){
    biasF[r] = bih[r * 64 + unit] + bhh[r * 64 + unit];
    #pragma unroll
    for (int d = 0; d < 3; d++) Wf[r][d] = Wih[(r * 64 + unit) * 3 + d];
  }

  for (int idx = tid; idx < 2 * 4 * LSTR; idx += 256)
    ((unsigned short*)sZ)[idx] = 0;
  for (int i4 = tid; i4 < 1536; i4 += 256){
    const int row = i4 >> 7, t4 = (i4 & 127) * 4;
    *(float4*)&sX[row * XS + t4] = *(const float4*)(x + (size_t)bbase * 1536 + row * 512 + t4);
  }
  __syncthreads();

  const int xrow = 3 * batch;
  float c = 0.f, h = 0.f;
  const f32x4 z4 = {0.f, 0.f, 0.f, 0.f};

#define FFCOMP(F, TIDX) do { \
    float x0_ = sX[xrow * XS + (TIDX)]; \
    float x1_ = sX[(xrow + 1) * XS + (TIDX)]; \
    float x2_ = sX[(xrow + 2) * XS + (TIDX)]; \
    _Pragma("unroll") \
    for (int r_ = 0; r_ < 4; r_++) \
      F[r_] = fmaf(Wf[r_][2], x2_, fmaf(Wf[r_][1], x1_, fmaf(Wf[r_][0], x0_, biasF[r_]))); \
  } while(0)

  f32x4 FBa, FBb;
  {
    const int t0_ = dir ? (TT - 1) : 0;
    FFCOMP(FBa, t0_);
  }

#define L0STEP(S, P, FC, FN) do { \
    const int p1_ = (P) ^ 1; \
    short8 bh0 = *(const short8*)&sZ[P][batch][     quad * 8]; \
    short8 bh1 = *(const short8*)&sZ[P][batch][32 + quad * 8]; \
    if (wv == 3 && lane < 32 && (S) > 0){ \
      const int tprev = dir ? (TT - (S)) : ((S) - 1); \
      const int br_ = lane >> 3, cc_ = lane & 7; \
      uint4 v_ = *(const uint4*)&sZ[P][br_][cc_ * 8]; \
      *(uint4*)(y0 + ((size_t)(bbase + br_) * TT + tprev) * 128 + dir * 64 + cc_ * 8) = v_; \
    } \
    f32x4 C0 = MF(aH[0][0], bh0, z4); \
    f32x4 C1 = MF(aH[1][0], bh0, z4); \
    f32x4 C2 = MF(aH[2][0], bh0, z4); \
    f32x4 C3 = MF(aH[3][0], bh0, z4); \
    C0 = MF(aH[0][1], bh1, C0); \
    C1 = MF(aH[1][1], bh1, C1); \
    C2 = MF(aH[2][1], bh1, C2); \
    C3 = MF(aH[3][1], bh1, C3); \
    { int sn_ = (S) + 1; if (sn_ > TT - 1) sn_ = TT - 1; \
      const int tn_ = dir ? (TT - 1 - sn_) : sn_; \
      FFCOMP(FN, tn_); \
    } \
    __builtin_amdgcn_sched_barrier(0); \
    { \
      float g0_ = (selB ? (selA ? C3[0] : C2[0]) : (selA ? C1[0] : C0[0])) + FC[0]; \
      float g1_ = (selB ? (selA ? C3[1] : C2[1]) : (selA ? C1[1] : C0[1])) + FC[1]; \
      float g2_ = (selB ? (selA ? C3[2] : C2[2]) : (selA ? C1[2] : C0[2])) + FC[2]; \
      float g3_ = (selB ? (selA ? C3[3] : C2[3]) : (selA ? C1[3] : C0[3])) + FC[3]; \
      float ii_ = sigx(g0_), ff_ = sigx(g1_), gg_ = tanhx(g2_), oo_ = sigx(g3_); \
      c = fmaf(ff_, c, ii_ * gg_); \
      h = oo_ * tanhx(c); \
      sZ[p1_][batch][unit] = (unsigned short)f2bf_u(h); \
    } \
    __builtin_amdgcn_sched_barrier(0); \
    lds_barrier(); \
  } while(0)

  for (int s = 0; s < TT; s += 2){
    L0STEP(s,     0, FBa, FBb);
    L0STEP(s + 1, 1, FBb, FBa);
  }
#undef L0STEP
#undef FFCOMP

  if (wv == 3 && lane < 32){
    const int tl = dir ? 0 : (TT - 1);
    const int br = lane >> 3, cc = lane & 7;
    uint4 v = *(const uint4*)&sZ[0][br][cc * 8];
    *(uint4*)(y0 + ((size_t)(bbase + br) * TT + tl) * 128 + dir * 64 + cc * 8) = v;
  }
}

// ==================== Layer 1 ====================
// 16 waves (1024 thr), 1 block/CU, 4 waves/SIMD. Wave wv owns ONE rowtile
// (units 4wv..4wv+3): C reg r = gate r of unit 4wv+quad directly -> no
// redistribution select. Cols 8-15 duplicate batches (broadcast bh reads);
// FF dual-step packs (s, s+1) in N, 4 swizzles/pair. Rec MFMAs init from
// G (bias+FF) -> no post-add.
__global__ __launch_bounds__(1024, 4) void lstm_l1(
    const unsigned short* __restrict__ y0,  // [B][T][128] bf16
    const float* __restrict__ Wih_f, const float* __restrict__ Whh_f,
    const float* __restrict__ bih_f, const float* __restrict__ bhh_f,
    const float* __restrict__ Wih_b, const float* __restrict__ Whh_b,
    const float* __restrict__ bih_b, const float* __restrict__ bhh_b,
    float* __restrict__ hT)                 // [B][128] fp32
{
  const int tid = threadIdx.x;
  const int wv = tid >> 6, lane = tid & 63;
  const int quad = lane >> 4, m16 = lane & 15;
  const int dir = blockIdx.y;
  const int bbase = blockIdx.x * 8;
  const float* Wih = dir ? Wih_b : Wih_f;
  const float* Whh = dir ? Whh_b : Whh_f;
  const float* bih = dir ? bih_b : bih_f;
  const float* bhh = dir ? bhh_b : bhh_f;

  __shared__ __align__(16) unsigned short sZ[2][8][LSTR];
  __shared__ __align__(16) unsigned short sY[4][8][LSTR];   // 4-slot y0 ring

  short8 aY[4], aH[2];
  f32x4 biasv;
  const int gm = (m16 & 3) * 64 + (m16 >> 2);
  const int g = gm + 4 * wv;
  #pragma unroll
  for (int kt = 0; kt < 4; kt++) aY[kt] = w8f32(Wih + g * 128 + kt * 32 + quad * 8);
  aH[0] = w8f32(Whh + g * 64 + quad * 8);
  aH[1] = w8f32(Whh + g * 64 + 32 + quad * 8);
  const int unit = 4 * wv + quad;
  #pragma unroll
  for (int r = 0; r < 4; r++) biasv[r] = bih[r * 64 + unit] + bhh[r * 64 + unit];

  for (int idx = tid; idx < 2 * 8 * LSTR; idx += 1024)
    ((unsigned short*)sZ)[idx] = 0;

  // staging: waves 0-7, lanes 0-15 -> 8 batch rows x 16 chunks
  const bool stager = (wv < 8) && (lane < 16);
  const size_t sgbase = (size_t)(bbase + (wv & 7)) * TT * 128 + (size_t)(lane & 15) * 8;
  float4 hA = make_float4(0.f,0.f,0.f,0.f), hB = make_float4(0.f,0.f,0.f,0.f);
  if (stager){
    #pragma unroll
    for (int k = 0; k < 4; k++){
      const int tk = dir ? (TT - 1 - k) : k;
      *(float4*)&sY[k][wv][lane * 8] = *(const float4*)(y0 + sgbase + (size_t)tk * 128);
    }
    const int t4 = dir ? (TT - 5) : 4, t5 = dir ? (TT - 6) : 5;
    hA = *(const float4*)(y0 + sgbase + (size_t)t4 * 128);
    hB = *(const float4*)(y0 + sgbase + (size_t)t5 * 128);
  }
  __syncthreads();

  const int m8 = m16 & 7;
  const bool sel0 = (m16 < 8);
  float c = 0.f, h = 0.f;

  const int SLOTU = 8 * LSTR;
  // per-lane y base: batch row m8, k-offset quad*8; lanes m16>=8 shift +1 slot
  const unsigned short* yb = &sY[0][0][0] + (sel0 ? 0 : SLOTU) + m8 * LSTR + quad * 8;

  // 4 FF MFMAs for pair at slot base SL (cols 0-7 step s, 8-15 step s+1)
#define FFMM(SL, FB) do { \
    short8 by0 = *(const short8*)(yb + (SL) * SLOTU); \
    short8 by1 = *(const short8*)(yb + (SL) * SLOTU + 32); \
    short8 by2 = *(const short8*)(yb + (SL) * SLOTU + 64); \
    short8 by3 = *(const short8*)(yb + (SL) * SLOTU + 96); \
    FB = MF(aY[0], by0, biasv); \
    FB = MF(aY[1], by1, FB); \
    FB = MF(aY[2], by2, FB); \
    FB = MF(aY[3], by3, FB); \
  } while(0)

  // redistribute FF pair (4 unconditional swizzles, selects on regs)
#define FFSWZ(FB, G0, G1) do { \
    float w0_ = SWZ(FB[0]), w1_ = SWZ(FB[1]), w2_ = SWZ(FB[2]), w3_ = SWZ(FB[3]); \
    G0[0] = sel0 ? FB[0] : w0_;  G0[1] = sel0 ? FB[1] : w1_; \
    G0[2] = sel0 ? FB[2] : w2_;  G0[3] = sel0 ? FB[3] : w3_; \
    G1[0] = sel0 ? w0_ : FB[0];  G1[1] = sel0 ? w1_ : FB[1]; \
    G1[2] = sel0 ? w2_ : FB[2];  G1[3] = sel0 ? w3_ : FB[3]; \
  } while(0)

  f32x4 Ga0, Ga1, Gb0, Gb1, FBT;
  FFMM(0, FBT);
  FFSWZ(FBT, Ga0, Ga1);
  lds_barrier();   // protect slot 0/1 reads from step-0/1 stager overwrite

#define NONLIN1(R, P1) do { \
    float ii_ = sigx((R)[0]), ff_ = sigx((R)[1]), gg_ = tanhx((R)[2]), oo_ = sigx((R)[3]); \
    c = fmaf(ff_, c, ii_ * gg_); \
    h = oo_ * tanhx(c); \
    if (sel0) sZ[P1][m8][unit] = (unsigned short)f2bf_u(h); \
  } while(0)

#define STAGE(S, WRSL, HOLD) do { \
    if (stager){ \
      *(float4*)&sY[WRSL][wv][lane * 8] = HOLD; \
      int sg_ = (S) + 6; if (sg_ > TT - 1) sg_ = TT - 1; \
      const int tg_ = dir ? (TT - 1 - sg_) : sg_; \
      HOLD = *(const float4*)(y0 + sgbase + (size_t)tg_ * 128); \
    } \
  } while(0)

  // even step: reads sZ[0], writes sZ[1]; issues next pair's FF MFMAs
#define L1STEPA(S, SLFF, WRSL, HOLD, GC) do { \
    short8 bh0 = *(const short8*)&sZ[0][m8][     quad * 8]; \
    short8 bh1 = *(const short8*)&sZ[0][m8][32 + quad * 8]; \
    f32x4 R = MF(aH[0], bh0, GC); \
    R = MF(aH[1], bh1, R); \
    FFMM(SLFF, FBT); \
    STAGE(S, WRSL, HOLD); \
    __builtin_amdgcn_sched_barrier(0); \
    NONLIN1(R, 1); \
    __builtin_amdgcn_sched_barrier(0); \
    lds_barrier(); \
  } while(0)

  // odd step: reads sZ[1], writes sZ[0]; swizzles next pair's FF into GN
#define L1STEPB(S, WRSL, HOLD, GC, GN0, GN1) do { \
    short8 bh0 = *(const short8*)&sZ[1][m8][     quad * 8]; \
    short8 bh1 = *(const short8*)&sZ[1][m8][32 + quad * 8]; \
    f32x4 R = MF(aH[0], bh0, GC); \
    R = MF(aH[1], bh1, R); \
    FFSWZ(FBT, GN0, GN1); \
    STAGE(S, WRSL, HOLD); \
    __builtin_amdgcn_sched_barrier(0); \
    NONLIN1(R, 0); \
    if ((S) == TT - 1 && sel0){ \
      hT[(size_t)(bbase + m8) * 128 + dir * 64 + unit] = h; \
    } \
    __builtin_amdgcn_sched_barrier(0); \
    lds_barrier(); \
  } while(0)

  for (int s = 0; s < TT; s += 4){
    L1STEPA(s,     2, 0, hA, Ga0);            // FF for pair (s+2,s+3) from slots 2/3
    L1STEPB(s + 1,    1, hB, Ga1, Gb0, Gb1);
    L1STEPA(s + 2, 0, 2, hA, Gb0);            // FF for pair (s+4,s+5) from slots 0/1
    L1STEPB(s + 3,    3, hB, Gb1, Ga0, Ga1);
  }
#undef L1STEPA
#undef L1STEPB
#undef STAGE
#undef NONLIN1
#undef FFSWZ
#undef FFMM
}

// ==================== FC head ====================
__global__ __launch_bounds__(256, 1) void fc_kernel(
    const float* __restrict__ hT,
    const float* __restrict__ w1, const float* __restrict__ b1,
    const float* __restrict__ w2, const float* __restrict__ b2,
    float* __restrict__ out)
{
  __shared__ float sh[4][64];
  const int wave = threadIdx.x >> 6, lane = threadIdx.x & 63;
  const int b = blockIdx.x * 4 + wave;
  float acc = b1[lane];
  const float* hrow = hT + (size_t)b * 128;
  #pragma unroll
  for (int k = 0; k < 128; k += 4){
    float4 h4 = *(const float4*)(hrow + k);
    float4 w4 = *(const float4*)(w1 + lane * 128 + k);
    acc = fmaf(w4.x, h4.x, acc);
    acc = fmaf(w4.y, h4.y, acc);
    acc = fmaf(w4.z, h4.z, acc);
    acc = fmaf(w4.w, h4.w, acc);
  }
  sh[wave][lane] = fmaxf(acc, 0.f);
  __syncthreads();
  if (lane < 2){
    float a = b2[lane];
    #pragma unroll
    for (int k = 0; k < 64; k++) a = fmaf(w2[lane * 64 + k], sh[wave][k], a);
    out[(size_t)b * 2 + lane] = a;
  }
}

extern "C" void kernel_launch(void* const* d_in, const int* in_sizes, int n_in,
                              void* d_out, int out_size, void* d_ws, size_t ws_size,
                              hipStream_t stream){
  (void)in_sizes; (void)n_in; (void)out_size; (void)ws_size;
  const float* x     = (const float*)d_in[0];
  const float* Wih0f = (const float*)d_in[1];
  const float* Whh0f = (const float*)d_in[2];
  const float* bih0f = (const float*)d_in[3];
  const float* bhh0f = (const float*)d_in[4];
  const float* Wih0b = (const float*)d_in[5];
  const float* Whh0b = (const float*)d_in[6];
  const float* bih0b = (const float*)d_in[7];
  const float* bhh0b = (const float*)d_in[8];
  const float* Wih1f = (const float*)d_in[9];
  const float* Whh1f = (const float*)d_in[10];
  const float* bih1f = (const float*)d_in[11];
  const float* bhh1f = (const float*)d_in[12];
  const float* Wih1b = (const float*)d_in[13];
  const float* Whh1b = (const float*)d_in[14];
  const float* bih1b = (const float*)d_in[15];
  const float* bhh1b = (const float*)d_in[16];
  const float* fc1W  = (const float*)d_in[17];
  const float* fc1b  = (const float*)d_in[18];
  const float* fc2W  = (const float*)d_in[19];
  const float* fc2b  = (const float*)d_in[20];
  float* out = (float*)d_out;

  unsigned short* y0 = (unsigned short*)d_ws;                       // 134,217,728 B
  float* hT = (float*)((char*)d_ws + (size_t)1024 * TT * 128 * 2);

  lstm_l0<<<dim3(256, 2), dim3(256), 0, stream>>>(x, Wih0f, Whh0f, bih0f, bhh0f,
                                                  Wih0b, Whh0b, bih0b, bhh0b, y0);
  lstm_l1<<<dim3(128, 2), dim3(1024), 0, stream>>>(y0, Wih1f, Whh1f, bih1f, bhh1f,
                                                   Wih1b, Whh1b, bih1b, bhh1b, hT);
  fc_kernel<<<dim3(256), dim3(256), 0, stream>>>(hT, fc1W, fc1b, fc2W, fc2b, out);
}

// Round 13
// 519.766 us; speedup vs baseline: 1.1344x; 1.1344x over previous
//
#include <hip/hip_runtime.h>
#include <stdint.h>

typedef __attribute__((ext_vector_type(8))) short short8;
typedef __attribute__((ext_vector_type(4))) float f32x4;

#define TT 512
#define LSTR 136   // sZ/sY row stride in ushorts: 272B -> spread banks
#define XS 516     // sX row stride in floats

static __device__ __forceinline__ uint32_t f2bf_u(float f){
  union { float f; uint32_t u; } v; v.f = f;
  return (v.u + 0x7fffu + ((v.u >> 16) & 1u)) >> 16;
}
static __device__ __forceinline__ short8 w8f32(const float* p){
  float4 a = *(const float4*)p;
  float4 b = *(const float4*)(p + 4);
  short8 r;
  r[0] = (short)f2bf_u(a.x); r[1] = (short)f2bf_u(a.y);
  r[2] = (short)f2bf_u(a.z); r[3] = (short)f2bf_u(a.w);
  r[4] = (short)f2bf_u(b.x); r[5] = (short)f2bf_u(b.y);
  r[6] = (short)f2bf_u(b.z); r[7] = (short)f2bf_u(b.w);
  return r;
}
// sigmoid via exp2+rcp: inf-safe (exp2->inf => rcp->0).
static __device__ __forceinline__ float sigx(float x){
  float e = __builtin_amdgcn_exp2f(-1.442695040888963f * x);
  return __builtin_amdgcn_rcpf(1.f + e);
}
// tanh(x) = 2*sigmoid(2x)-1: no clamp needed.
static __device__ __forceinline__ float tanhx(float x){
  float e = __builtin_amdgcn_exp2f(-2.885390081777927f * x);
  return fmaf(__builtin_amdgcn_rcpf(1.f + e), 2.f, -1.f);
}
// LDS-only barrier: waits ds ops, leaves global loads/stores in flight.
static __device__ __forceinline__ void lds_barrier(){
  asm volatile("s_waitcnt lgkmcnt(0)" ::: "memory");
  __builtin_amdgcn_s_barrier();
}
#define MF(A,B,C) __builtin_amdgcn_mfma_f32_16x16x32_bf16((A),(B),(C),0,0,0)
// lane^8 exchange (convergent -> must be issued unconditionally)
#define SWZ(x) __int_as_float(__builtin_amdgcn_ds_swizzle(__float_as_int(x), 0x201F))

// ==================== Layer 0 ====================
// 256 thr / 4 waves / 4 batches; grid (256,2) -> 2 blocks/CU. 4 MFMA chains
// 0-init; own-unit VALU FF (12 fmaf); cndmask chain select; 4-row sZ with
// broadcast reads. y0 store distributed: wave w stores batch row w (lanes 0-7).
__global__ __launch_bounds__(256, 2) void lstm_l0(
    const float* __restrict__ x,   // [B][3][T]
    const float* __restrict__ Wih_f, const float* __restrict__ Whh_f,
    const float* __restrict__ bih_f, const float* __restrict__ bhh_f,
    const float* __restrict__ Wih_b, const float* __restrict__ Whh_b,
    const float* __restrict__ bih_b, const float* __restrict__ bhh_b,
    unsigned short* __restrict__ y0)  // [B][T][128] bf16
{
  const int tid = threadIdx.x;
  const int wv = tid >> 6, lane = tid & 63;
  const int quad = lane >> 4, m16 = lane & 15;
  const int dir = blockIdx.y;
  const int bbase = blockIdx.x * 4;
  const float* Wih = dir ? Wih_b : Wih_f;
  const float* Whh = dir ? Whh_b : Whh_f;
  const float* bih = dir ? bih_b : bih_f;
  const float* bhh = dir ? bhh_b : bhh_f;

  __shared__ __align__(16) unsigned short sZ[2][4][LSTR];
  __shared__ __align__(16) float sX[12 * XS];

  const int copy = m16 >> 2;
  const int batch = m16 & 3;
  const int unit = 16 * wv + 4 * copy + quad;
  const bool selA = (copy & 1) != 0;
  const bool selB = (copy & 2) != 0;

  short8 aH[4][2];
  const int gm = (m16 & 3) * 64 + (m16 >> 2);
  #pragma unroll
  for (int k = 0; k < 4; k++){
    const int g = gm + 4 * (4 * wv + k);
    aH[k][0] = w8f32(Whh + g * 64 + quad * 8);
    aH[k][1] = w8f32(Whh + g * 64 + 32 + quad * 8);
  }
  float Wf[4][3];
  f32x4 biasF;
  #pragma unroll
  for (int r = 0; r < 4; r++){
    biasF[r] = bih[r * 64 + unit] + bhh[r * 64 + unit];
    #pragma unroll
    for (int d = 0; d < 3; d++) Wf[r][d] = Wih[(r * 64 + unit) * 3 + d];
  }

  for (int idx = tid; idx < 2 * 4 * LSTR; idx += 256)
    ((unsigned short*)sZ)[idx] = 0;
  for (int i4 = tid; i4 < 1536; i4 += 256){
    const int row = i4 >> 7, t4 = (i4 & 127) * 4;
    *(float4*)&sX[row * XS + t4] = *(const float4*)(x + (size_t)bbase * 1536 + row * 512 + t4);
  }
  __syncthreads();

  const int xrow = 3 * batch;
  float c = 0.f, h = 0.f;
  const f32x4 z4 = {0.f, 0.f, 0.f, 0.f};

#define FFCOMP(F, TIDX) do { \
    float x0_ = sX[xrow * XS + (TIDX)]; \
    float x1_ = sX[(xrow + 1) * XS + (TIDX)]; \
    float x2_ = sX[(xrow + 2) * XS + (TIDX)]; \
    _Pragma("unroll") \
    for (int r_ = 0; r_ < 4; r_++) \
      F[r_] = fmaf(Wf[r_][2], x2_, fmaf(Wf[r_][1], x1_, fmaf(Wf[r_][0], x0_, biasF[r_]))); \
  } while(0)

  f32x4 FBa, FBb;
  {
    const int t0_ = dir ? (TT - 1) : 0;
    FFCOMP(FBa, t0_);
  }

#define L0STEP(S, P, FC, FN) do { \
    const int p1_ = (P) ^ 1; \
    short8 bh0 = *(const short8*)&sZ[P][batch][     quad * 8]; \
    short8 bh1 = *(const short8*)&sZ[P][batch][32 + quad * 8]; \
    if (lane < 8 && (S) > 0){ \
      const int tprev = dir ? (TT - (S)) : ((S) - 1); \
      uint4 v_ = *(const uint4*)&sZ[P][wv][lane * 8]; \
      *(uint4*)(y0 + ((size_t)(bbase + wv) * TT + tprev) * 128 + dir * 64 + lane * 8) = v_; \
    } \
    f32x4 C0 = MF(aH[0][0], bh0, z4); \
    f32x4 C1 = MF(aH[1][0], bh0, z4); \
    f32x4 C2 = MF(aH[2][0], bh0, z4); \
    f32x4 C3 = MF(aH[3][0], bh0, z4); \
    C0 = MF(aH[0][1], bh1, C0); \
    C1 = MF(aH[1][1], bh1, C1); \
    C2 = MF(aH[2][1], bh1, C2); \
    C3 = MF(aH[3][1], bh1, C3); \
    { int sn_ = (S) + 1; if (sn_ > TT - 1) sn_ = TT - 1; \
      const int tn_ = dir ? (TT - 1 - sn_) : sn_; \
      FFCOMP(FN, tn_); \
    } \
    __builtin_amdgcn_sched_barrier(0); \
    { \
      float g0_ = (selB ? (selA ? C3[0] : C2[0]) : (selA ? C1[0] : C0[0])) + FC[0]; \
      float g1_ = (selB ? (selA ? C3[1] : C2[1]) : (selA ? C1[1] : C0[1])) + FC[1]; \
      float g2_ = (selB ? (selA ? C3[2] : C2[2]) : (selA ? C1[2] : C0[2])) + FC[2]; \
      float g3_ = (selB ? (selA ? C3[3] : C2[3]) : (selA ? C1[3] : C0[3])) + FC[3]; \
      float ii_ = sigx(g0_), ff_ = sigx(g1_), gg_ = tanhx(g2_), oo_ = sigx(g3_); \
      c = fmaf(ff_, c, ii_ * gg_); \
      h = oo_ * tanhx(c); \
      sZ[p1_][batch][unit] = (unsigned short)f2bf_u(h); \
    } \
    __builtin_amdgcn_sched_barrier(0); \
    lds_barrier(); \
  } while(0)

  for (int s = 0; s < TT; s += 2){
    L0STEP(s,     0, FBa, FBb);
    L0STEP(s + 1, 1, FBb, FBa);
  }
#undef L0STEP
#undef FFCOMP

  if (lane < 8){
    const int tl = dir ? 0 : (TT - 1);
    uint4 v = *(const uint4*)&sZ[0][wv][lane * 8];
    *(uint4*)(y0 + ((size_t)(bbase + wv) * TT + tl) * 128 + dir * 64 + lane * 8) = v;
  }
}

// ==================== Layer 1 ====================
// (round-11 best) Dual-step FF: MFMA N-cols 0-7 = batches @ step s, 8-15 =
// batches @ s+1. One 8-MFMA FF set serves TWO steps. Lane^8 ds_swizzle
// redistribution one pair ahead, off the critical path. Rec MFMAs 0-init;
// gate base (bias+FF) added post-select.
__global__ __launch_bounds__(512, 2) void lstm_l1(
    const unsigned short* __restrict__ y0,  // [B][T][128] bf16
    const float* __restrict__ Wih_f, const float* __restrict__ Whh_f,
    const float* __restrict__ bih_f, const float* __restrict__ bhh_f,
    const float* __restrict__ Wih_b, const float* __restrict__ Whh_b,
    const float* __restrict__ bih_b, const float* __restrict__ bhh_b,
    float* __restrict__ hT)                 // [B][128] fp32
{
  const int tid = threadIdx.x;
  const int wv = tid >> 6, lane = tid & 63;
  const int quad = lane >> 4, m16 = lane & 15;
  const int dir = blockIdx.y;
  const int bbase = blockIdx.x * 8;
  const float* Wih = dir ? Wih_b : Wih_f;
  const float* Whh = dir ? Whh_b : Whh_f;
  const float* bih = dir ? bih_b : bih_f;
  const float* bhh = dir ? bhh_b : bhh_f;

  __shared__ __align__(16) unsigned short sZ[2][8][LSTR];
  __shared__ __align__(16) unsigned short sY[4][8][LSTR];   // 4-slot y0 ring

  short8 aY[2][4], aH[2][2];
  f32x4 biasv[2];
  const int gm = (m16 & 3) * 64 + (m16 >> 2);
  #pragma unroll
  for (int i = 0; i < 2; i++){
    const int rt = 2 * wv + i;
    const int g = gm + 4 * rt;
    #pragma unroll
    for (int kt = 0; kt < 4; kt++) aY[i][kt] = w8f32(Wih + g * 128 + kt * 32 + quad * 8);
    aH[i][0] = w8f32(Whh + g * 64 + quad * 8);
    aH[i][1] = w8f32(Whh + g * 64 + 32 + quad * 8);
    const int gu = 4 * rt + quad;
    #pragma unroll
    for (int r = 0; r < 4; r++) biasv[i][r] = bih[r * 64 + gu] + bhh[r * 64 + gu];
  }

  for (int idx = tid; idx < 2 * 8 * LSTR; idx += 512)
    ((unsigned short*)sZ)[idx] = 0;

  // prologue staging: slots 0..3 <- y(0..3); holds <- y(4), y(5)
  const bool stager = (lane < 16);
  const size_t sgbase = (size_t)(bbase + wv) * TT * 128 + (size_t)lane * 8;
  float4 hA = make_float4(0.f,0.f,0.f,0.f), hB = make_float4(0.f,0.f,0.f,0.f);
  if (stager){
    #pragma unroll
    for (int k = 0; k < 4; k++){
      const int tk = dir ? (TT - 1 - k) : k;
      *(float4*)&sY[k][wv][lane * 8] = *(const float4*)(y0 + sgbase + (size_t)tk * 128);
    }
    const int t4 = dir ? (TT - 5) : 4, t5 = dir ? (TT - 6) : 5;
    hA = *(const float4*)(y0 + sgbase + (size_t)t4 * 128);
    hB = *(const float4*)(y0 + sgbase + (size_t)t5 * 128);
  }
  __syncthreads();

  const int m8 = m16 & 7;
  const bool sel0 = (m16 < 8);
  const int colw = 8 * wv + quad + ((m16 >> 3) << 2);
  float c = 0.f, h = 0.f;
  const f32x4 z4 = {0.f, 0.f, 0.f, 0.f};

  const int SLOTU = 8 * LSTR;
  // per-lane y base: batch row m8, k-offset quad*8; lanes m16>=8 shift +1 slot
  const unsigned short* yb = &sY[0][0][0] + (sel0 ? 0 : SLOTU) + m8 * LSTR + quad * 8;

  // 8 FF MFMAs for pair at slot base SL (cols 0-7 step s, 8-15 step s+1)
#define FFMM(SL, FB0, FB1) do { \
    short8 by0 = *(const short8*)(yb + (SL) * SLOTU); \
    short8 by1 = *(const short8*)(yb + (SL) * SLOTU + 32); \
    short8 by2 = *(const short8*)(yb + (SL) * SLOTU + 64); \
    short8 by3 = *(const short8*)(yb + (SL) * SLOTU + 96); \
    FB0 = MF(aY[0][0], by0, biasv[0]); \
    FB1 = MF(aY[1][0], by0, biasv[1]); \
    FB0 = MF(aY[0][1], by1, FB0);  FB1 = MF(aY[1][1], by1, FB1); \
    FB0 = MF(aY[0][2], by2, FB0);  FB1 = MF(aY[1][2], by2, FB1); \
    FB0 = MF(aY[0][3], by3, FB0);  FB1 = MF(aY[1][3], by3, FB1); \
  } while(0)

  // redistribute FF pair: G0 (step s base), G1 (step s+1 base). All swizzles
  // unconditional (convergent op), selects on register values.
#define FFSWZ(FB0, FB1, G0, G1) do { \
    float w10_ = SWZ(FB1[0]), w11_ = SWZ(FB1[1]), w12_ = SWZ(FB1[2]), w13_ = SWZ(FB1[3]); \
    float w00_ = SWZ(FB0[0]), w01_ = SWZ(FB0[1]), w02_ = SWZ(FB0[2]), w03_ = SWZ(FB0[3]); \
    G0[0] = sel0 ? FB0[0] : w10_;  G0[1] = sel0 ? FB0[1] : w11_; \
    G0[2] = sel0 ? FB0[2] : w12_;  G0[3] = sel0 ? FB0[3] : w13_; \
    G1[0] = sel0 ? w00_ : FB1[0];  G1[1] = sel0 ? w01_ : FB1[1]; \
    G1[2] = sel0 ? w02_ : FB1[2];  G1[3] = sel0 ? w03_ : FB1[3]; \
  } while(0)

  f32x4 Ga0, Ga1, Gb0, Gb1, FBT0, FBT1;
  // FF(0),FF(1) from slots 0/1
  FFMM(0, FBT0, FBT1);
  FFSWZ(FBT0, FBT1, Ga0, Ga1);
  lds_barrier();   // protect slot 0/1 reads from step-0/1 stager overwrite

#define NONLIN1(R0, R1, GC, P1) do { \
    float g0_ = (sel0 ? (R0)[0] : (R1)[0]) + GC[0]; \
    float g1_ = (sel0 ? (R0)[1] : (R1)[1]) + GC[1]; \
    float g2_ = (sel0 ? (R0)[2] : (R1)[2]) + GC[2]; \
    float g3_ = (sel0 ? (R0)[3] : (R1)[3]) + GC[3]; \
    float ii_ = sigx(g0_), ff_ = sigx(g1_), gg_ = tanhx(g2_), oo_ = sigx(g3_); \
    c = fmaf(ff_, c, ii_ * gg_); \
    h = oo_ * tanhx(c); \
    sZ[P1][m8][colw] = (unsigned short)f2bf_u(h); \
  } while(0)

#define STAGE(S, WRSL, HOLD) do { \
    if (stager){ \
      *(float4*)&sY[WRSL][wv][lane * 8] = HOLD; \
      int sg_ = (S) + 6; if (sg_ > TT - 1) sg_ = TT - 1; \
      const int tg_ = dir ? (TT - 1 - sg_) : sg_; \
      HOLD = *(const float4*)(y0 + sgbase + (size_t)tg_ * 128); \
    } \
  } while(0)

  // even step: reads sZ[0], writes sZ[1]; issues next pair's FF MFMAs
#define L1STEPA(S, SLFF, WRSL, HOLD, GC) do { \
    short8 bh0 = *(const short8*)&sZ[0][m8][     quad * 8]; \
    short8 bh1 = *(const short8*)&sZ[0][m8][32 + quad * 8]; \
    f32x4 R0 = MF(aH[0][0], bh0, z4); \
    f32x4 R1 = MF(aH[1][0], bh0, z4); \
    R0 = MF(aH[0][1], bh1, R0); \
    R1 = MF(aH[1][1], bh1, R1); \
    FFMM(SLFF, FBT0, FBT1); \
    STAGE(S, WRSL, HOLD); \
    __builtin_amdgcn_sched_barrier(0); \
    NONLIN1(R0, R1, GC, 1); \
    __builtin_amdgcn_sched_barrier(0); \
    lds_barrier(); \
  } while(0)

  // odd step: reads sZ[1], writes sZ[0]; swizzles next pair's FF into GN
#define L1STEPB(S, WRSL, HOLD, GC, GN0, GN1) do { \
    short8 bh0 = *(const short8*)&sZ[1][m8][     quad * 8]; \
    short8 bh1 = *(const short8*)&sZ[1][m8][32 + quad * 8]; \
    f32x4 R0 = MF(aH[0][0], bh0, z4); \
    f32x4 R1 = MF(aH[1][0], bh0, z4); \
    R0 = MF(aH[0][1], bh1, R0); \
    R1 = MF(aH[1][1], bh1, R1); \
    FFSWZ(FBT0, FBT1, GN0, GN1); \
    STAGE(S, WRSL, HOLD); \
    __builtin_amdgcn_sched_barrier(0); \
    NONLIN1(R0, R1, GC, 0); \
    if ((S) == TT - 1){ \
      hT[(size_t)(bbase + m8) * 128 + dir * 64 + colw] = h; \
    } \
    __builtin_amdgcn_sched_barrier(0); \
    lds_barrier(); \
  } while(0)

  for (int s = 0; s < TT; s += 4){
    L1STEPA(s,     2, 0, hA, Ga0);            // FF for pair (s+2,s+3) from slots 2/3
    L1STEPB(s + 1,    1, hB, Ga1, Gb0, Gb1);
    L1STEPA(s + 2, 0, 2, hA, Gb0);            // FF for pair (s+4,s+5) from slots 0/1
    L1STEPB(s + 3,    3, hB, Gb1, Ga0, Ga1);
  }
#undef L1STEPA
#undef L1STEPB
#undef STAGE
#undef NONLIN1
#undef FFSWZ
#undef FFMM
}

// ==================== FC head ====================
__global__ __launch_bounds__(256, 1) void fc_kernel(
    const float* __restrict__ hT,
    const float* __restrict__ w1, const float* __restrict__ b1,
    const float* __restrict__ w2, const float* __restrict__ b2,
    float* __restrict__ out)
{
  __shared__ float sh[4][64];
  const int wave = threadIdx.x >> 6, lane = threadIdx.x & 63;
  const int b = blockIdx.x * 4 + wave;
  float acc = b1[lane];
  const float* hrow = hT + (size_t)b * 128;
  #pragma unroll
  for (int k = 0; k < 128; k += 4){
    float4 h4 = *(const float4*)(hrow + k);
    float4 w4 = *(const float4*)(w1 + lane * 128 + k);
    acc = fmaf(w4.x, h4.x, acc);
    acc = fmaf(w4.y, h4.y, acc);
    acc = fmaf(w4.z, h4.z, acc);
    acc = fmaf(w4.w, h4.w, acc);
  }
  sh[wave][lane] = fmaxf(acc, 0.f);
  __syncthreads();
  if (lane < 2){
    float a = b2[lane];
    #pragma unroll
    for (int k = 0; k < 64; k++) a = fmaf(w2[lane * 64 + k], sh[wave][k], a);
    out[(size_t)b * 2 + lane] = a;
  }
}

extern "C" void kernel_launch(void* const* d_in, const int* in_sizes, int n_in,
                              void* d_out, int out_size, void* d_ws, size_t ws_size,
                              hipStream_t stream){
  (void)in_sizes; (void)n_in; (void)out_size; (void)ws_size;
  const float* x     = (const float*)d_in[0];
  const float* Wih0f = (const float*)d_in[1];
  const float* Whh0f = (const float*)d_in[2];
  const float* bih0f = (const float*)d_in[3];
  const float* bhh0f = (const float*)d_in[4];
  const float* Wih0b = (const float*)d_in[5];
  const float* Whh0b = (const float*)d_in[6];
  const float* bih0b = (const float*)d_in[7];
  const float* bhh0b = (const float*)d_in[8];
  const float* Wih1f = (const float*)d_in[9];
  const float* Whh1f = (const float*)d_in[10];
  const float* bih1f = (const float*)d_in[11];
  const float* bhh1f = (const float*)d_in[12];
  const float* Wih1b = (const float*)d_in[13];
  const float* Whh1b = (const float*)d_in[14];
  const float* bih1b = (const float*)d_in[15];
  const float* bhh1b = (const float*)d_in[16];
  const float* fc1W  = (const float*)d_in[17];
  const float* fc1b  = (const float*)d_in[18];
  const float* fc2W  = (const float*)d_in[19];
  const float* fc2b  = (const float*)d_in[20];
  float* out = (float*)d_out;

  unsigned short* y0 = (unsigned short*)d_ws;                       // 134,217,728 B
  float* hT = (float*)((char*)d_ws + (size_t)1024 * TT * 128 * 2);

  lstm_l0<<<dim3(256, 2), dim3(256), 0, stream>>>(x, Wih0f, Whh0f, bih0f, bhh0f,
                                                  Wih0b, Whh0b, bih0b, bhh0b, y0);
  lstm_l1<<<dim3(128, 2), dim3(512), 0, stream>>>(y0, Wih1f, Whh1f, bih1f, bhh1f,
                                                  Wih1b, Whh1b, bih1b, bhh1b, hT);
  fc_kernel<<<dim3(256), dim3(256), 0, stream>>>(hT, fc1W, fc1b, fc2W, fc2b, out);
}